// Round 2
// baseline (556.404 us; speedup 1.0000x reference)
//
#include <hip/hip_runtime.h>
#include <hip/hip_cooperative_groups.h>

namespace cg = cooperative_groups;

#define CHUNK 400
#define LWIN 50
#define JUMP 8
#define NCH 128
#define BCH 128
#define HCH 512
#define NBLK 14
#define BUF 516
#define SHIFT 508   // BUF - JUMP
#define EPSV 1e-8f
#define NWG 136     // 8 front WGs + 128 copy WGs; >= 129 stage chunks

// stage1: y1n[t0..t0+nf) = cLN(PReLU(w1 @ xs)); xs is LDS [4][128]
__device__ __forceinline__ void stage1_core(
    int tid, int lane, int wid, int t0, int nf,
    const float* __restrict__ w1b, float aPr,
    const float* __restrict__ gv, const float* __restrict__ bv,
    float* __restrict__ yout,
    float* redf /*[8*4*2]*/, float* statsf /*[4*2]*/, const float* xsv)
{
    float acc[4] = {0.f, 0.f, 0.f, 0.f};
    const float4* __restrict__ wr = (const float4*)(w1b + tid * BCH);
    const float4* __restrict__ xv = (const float4*)xsv;
    #pragma unroll 4
    for (int c4 = 0; c4 < 32; ++c4) {
        float4 w = wr[c4];
        #pragma unroll
        for (int f = 0; f < 4; ++f) {
            float4 x = xv[f * 32 + c4];
            acc[f] += w.x * x.x + w.y * x.y + w.z * x.z + w.w * x.w;
        }
    }
    #pragma unroll
    for (int f = 0; f < 4; ++f) acc[f] = acc[f] >= 0.f ? acc[f] : aPr * acc[f];
    for (int f = 0; f < nf; ++f) {
        float s = acc[f], q = acc[f] * acc[f];
        #pragma unroll
        for (int o = 32; o; o >>= 1) { s += __shfl_xor(s, o); q += __shfl_xor(q, o); }
        if (lane == 0) { redf[(wid * 4 + f) * 2] = s; redf[(wid * 4 + f) * 2 + 1] = q; }
    }
    __syncthreads();
    if (tid < nf) {
        float s = 0.f, q = 0.f;
        #pragma unroll
        for (int w = 0; w < 8; ++w) { s += redf[(w * 4 + tid) * 2]; q += redf[(w * 4 + tid) * 2 + 1]; }
        float mean = s * (1.f / HCH);
        float var = q * (1.f / HCH) - mean * mean;
        statsf[tid * 2] = mean; statsf[tid * 2 + 1] = rsqrtf(var + EPSV);
    }
    __syncthreads();
    float gg = gv[tid], bb = bv[tid];
    for (int f = 0; f < nf; ++f)
        yout[(t0 + f) * HCH + tid] = gg * (acc[f] - statsf[f * 2]) * statsf[f * 2 + 1] + bb;
}

__global__ __launch_bounds__(512) void k_fused(
    const float* __restrict__ mixture, const float* __restrict__ inEnc,
    const float* __restrict__ inLn, const float* __restrict__ Wenc,
    const float* __restrict__ lng, const float* __restrict__ lnb,
    const float* __restrict__ Wbn, const float* __restrict__ w1,
    const float* __restrict__ p1, const float* __restrict__ g1,
    const float* __restrict__ b1, const float* __restrict__ dwc,
    const float* __restrict__ p2, const float* __restrict__ g2,
    const float* __restrict__ b2, const float* __restrict__ w2,
    const float* __restrict__ Wmask, const float* __restrict__ Wdec,
    float* __restrict__ est, float* __restrict__ outEnc, float* __restrict__ outLn,
    float* __restrict__ enc, float* __restrict__ xA, float* __restrict__ xB,
    float* __restrict__ y1nA, float* __restrict__ y1nB)
{
    cg::grid_group grid = cg::this_grid();
    __shared__ float xs[4 * BCH];        // x frames for stage1 / ns for front / sw for dec
    __shared__ float ys[4 * 528];        // stage2 normalized, 132-stride padded groups
    __shared__ float redf[8 * 4 * 2];
    __shared__ float statsf[4 * 2];

    const int wg = blockIdx.x;
    const int tid = threadIdx.x;
    const int lane = tid & 63, wid = tid >> 6;

    // ================= I0: encoder+front (wg<8) | buffer shifts (wg 8..135) =====
    if (wg < 8) {
        int t = wg;
        float e = 0.f;
        if (tid < 128) {
            int c = tid;
            const float* w = Wenc + c * 100;
            const float* m = mixture + t * LWIN;
            #pragma unroll 10
            for (int l = 0; l < LWIN; ++l) e += m[l] * w[l] + m[CHUNK + l] * w[LWIN + l];
            e = fmaxf(e, 0.f);
            enc[c * JUMP + t] = e;
            outEnc[c * BUF + SHIFT + t] = e;
            float s = e, q = e * e;
            #pragma unroll
            for (int o = 32; o; o >>= 1) { s += __shfl_xor(s, o); q += __shfl_xor(q, o); }
            if (lane == 0) { redf[(wid * 4) * 2] = s; redf[(wid * 4) * 2 + 1] = q; }
        }
        __syncthreads();
        if (tid < 128) {
            float S = redf[0] + redf[8], Q = redf[1] + redf[9];
            float mean = S * (1.f / NCH);
            float var = Q * (1.f / NCH) - mean * mean;
            float r = rsqrtf(var + EPSV);
            xs[tid] = lng[tid] * (e - mean) * r + lnb[tid];
        }
        __syncthreads();
        if (tid < 128) {
            float acc = 0.f;
            const float4* wr = (const float4*)(Wbn + tid * NCH);
            const float4* nv = (const float4*)xs;
            #pragma unroll 8
            for (int j4 = 0; j4 < 32; ++j4) {
                float4 w = wr[j4]; float4 x = nv[j4];
                acc += w.x * x.x + w.y * x.y + w.z * x.z + w.w * x.w;
            }
            outLn[tid * BUF + SHIFT + t] = acc;
            xA[(SHIFT + t) * BCH + tid] = acc;
        }
    } else {
        int c = wg - 8;
        if (tid < SHIFT) {
            outEnc[c * BUF + tid] = inEnc[c * BUF + tid + JUMP];
            float v = inLn[c * BUF + tid + JUMP];
            outLn[c * BUF + tid] = v;
            xA[tid * BCH + c] = v;
        }
    }
    grid.sync();

    // ================= I1: stage1 of block 0 ====================================
    {
        int t0 = 4 * wg;
        if (t0 < BUF) {
            int nf = min(4, BUF - t0);
            for (int idx = tid; idx < nf * BCH; idx += 512) xs[idx] = xA[t0 * BCH + idx];
            __syncthreads();
            stage1_core(tid, lane, wid, t0, nf, w1, p1[0], g1, b1, y1nA, redf, statsf, xs);
        }
    }
    grid.sync();

    // ================= I2..I15: stage2(i) fused with stage1(i+1) / mask+dec =====
    const float* xin = xA;  float* xout = xB;
    const float* ycur = y1nA; float* ynext = y1nB;
    int T = BUF;
    for (int i = 0; i < NBLK; ++i) {
        int d = 1 << (i % 7);
        int Tout = T - 2 * d;
        int t0 = 4 * wg;
        if (t0 < Tout) {
            int nf = min(4, Tout - t0);
            // ---- depthwise conv + PReLU ----
            const float* dwb = dwc + (size_t)i * HCH * 3;
            float d0 = dwb[tid * 3], d1 = dwb[tid * 3 + 1], d2 = dwb[tid * 3 + 2];
            float a2 = p2[i];
            float y[4];
            for (int f = 0; f < nf; ++f) {
                int t = t0 + f;
                float v = d0 * ycur[t * HCH + tid] + d1 * ycur[(t + d) * HCH + tid]
                        + d2 * ycur[(t + 2 * d) * HCH + tid];
                y[f] = v >= 0.f ? v : a2 * v;
            }
            // ---- cLN over H ----
            for (int f = 0; f < nf; ++f) {
                float s = y[f], q = y[f] * y[f];
                #pragma unroll
                for (int o = 32; o; o >>= 1) { s += __shfl_xor(s, o); q += __shfl_xor(q, o); }
                if (lane == 0) { redf[(wid * 4 + f) * 2] = s; redf[(wid * 4 + f) * 2 + 1] = q; }
            }
            __syncthreads();
            if (tid < nf) {
                float s = 0.f, q = 0.f;
                #pragma unroll
                for (int w = 0; w < 8; ++w) { s += redf[(w * 4 + tid) * 2]; q += redf[(w * 4 + tid) * 2 + 1]; }
                float mean = s * (1.f / HCH);
                float var = q * (1.f / HCH) - mean * mean;
                statsf[tid * 2] = mean; statsf[tid * 2 + 1] = rsqrtf(var + EPSV);
            }
            __syncthreads();
            {
                float gg = g2[i * HCH + tid], bb = b2[i * HCH + tid];
                int pidx = (tid >> 7) * 132 + (tid & 127);
                for (int f = 0; f < nf; ++f)
                    ys[f * 528 + pidx] = gg * (y[f] - statsf[f * 2]) * statsf[f * 2 + 1] + bb;
            }
            __syncthreads();
            // ---- w2 GEMM (K split by 4) + residual ----
            int c = tid >> 2, p = tid & 3;
            float acc[4] = {0.f, 0.f, 0.f, 0.f};
            const float4* wr = (const float4*)(w2 + (size_t)i * BCH * HCH + c * HCH + p * 128);
            const float* yb = ys + p * 132;
            #pragma unroll 4
            for (int j4 = 0; j4 < 32; ++j4) {
                float4 w = wr[j4];
                #pragma unroll
                for (int f = 0; f < 4; ++f) {
                    float4 x = *(const float4*)&yb[f * 528 + j4 * 4];
                    acc[f] += w.x * x.x + w.y * x.y + w.z * x.z + w.w * x.w;
                }
            }
            for (int f = 0; f < nf; ++f) {
                acc[f] += __shfl_xor(acc[f], 1);
                acc[f] += __shfl_xor(acc[f], 2);
            }
            if (p == 0) {
                for (int f = 0; f < nf; ++f) {
                    int t = t0 + f;
                    float xv = xin[(t + 2 * d) * BCH + c] + acc[f];
                    xout[t * BCH + c] = xv;
                    xs[f * BCH + c] = xv;
                }
            }
            __syncthreads();
            // ---- fused next stage1 (or mask+decoder on the last block) ----
            if (i < NBLK - 1) {
                stage1_core(tid, lane, wid, t0, nf,
                            w1 + (size_t)(i + 1) * HCH * BCH, p1[i + 1],
                            g1 + (i + 1) * HCH, b1 + (i + 1) * HCH, ynext, redf, statsf, xs);
            } else {
                int cc = tid & 127, f = tid >> 7;
                float m = 0.f;
                const float4* wm = (const float4*)(Wmask + cc * BCH);
                const float4* xv = (const float4*)(xs + f * BCH);
                #pragma unroll 8
                for (int j4 = 0; j4 < 32; ++j4) {
                    float4 w = wm[j4]; float4 x = xv[j4];
                    m += w.x * x.x + w.y * x.y + w.z * x.z + w.w * x.w;
                }
                m = fmaxf(m, 0.f);
                ys[f * BCH + cc] = m * enc[cc * JUMP + (t0 + f)];
                __syncthreads();
                if (tid < 4 * LWIN) {
                    int ff = tid / LWIN, l = tid % LWIN;
                    float e = 0.f;
                    const float4* wd = (const float4*)(Wdec + l * NCH);
                    const float4* sv = (const float4*)(ys + ff * BCH);
                    #pragma unroll 8
                    for (int j4 = 0; j4 < 32; ++j4) {
                        float4 w = wd[j4]; float4 x = sv[j4];
                        e += w.x * x.x + w.y * x.y + w.z * x.z + w.w * x.w;
                    }
                    est[(t0 + ff) * LWIN + l] = e;
                }
            }
        }
        if (i < NBLK - 1) grid.sync();
        T = Tout;
        const float* tf = xin; xin = xout; xout = (float*)tf;
        const float* ty = ycur; ycur = ynext; ynext = (float*)ty;
    }
}

extern "C" void kernel_launch(void* const* d_in, const int* in_sizes, int n_in,
                              void* d_out, int out_size, void* d_ws, size_t ws_size,
                              hipStream_t stream) {
    const float* mixture = (const float*)d_in[0];
    const float* inEnc   = (const float*)d_in[1];
    const float* inLn    = (const float*)d_in[2];
    const float* Wenc    = (const float*)d_in[3];
    const float* lng     = (const float*)d_in[4];
    const float* lnb     = (const float*)d_in[5];
    const float* Wbn     = (const float*)d_in[6];
    const float* w1      = (const float*)d_in[7];
    const float* p1      = (const float*)d_in[8];
    const float* g1      = (const float*)d_in[9];
    const float* b1      = (const float*)d_in[10];
    const float* dwc     = (const float*)d_in[11];
    const float* p2      = (const float*)d_in[12];
    const float* g2      = (const float*)d_in[13];
    const float* b2      = (const float*)d_in[14];
    const float* w2      = (const float*)d_in[15];
    const float* Wmask   = (const float*)d_in[16];
    const float* Wdec    = (const float*)d_in[17];

    float* est    = (float*)d_out;
    float* outEnc = est + CHUNK;
    float* outLn  = outEnc + NCH * BUF;

    float* ws    = (float*)d_ws;
    float* enc   = ws;                       // 1024
    float* xA    = enc + NCH * JUMP;         // 66048
    float* xB    = xA + BUF * BCH;           // 66048
    float* y1nA  = xB + BUF * BCH;           // 264192
    float* y1nB  = y1nA + BUF * HCH;         // 264192

    void* args[] = { &mixture, &inEnc, &inLn, &Wenc, &lng, &lnb, &Wbn, &w1, &p1,
                     &g1, &b1, &dwc, &p2, &g2, &b2, &w2, &Wmask, &Wdec,
                     &est, &outEnc, &outLn, &enc, &xA, &xB, &y1nA, &y1nB };
    hipLaunchCooperativeKernel((const void*)k_fused, dim3(NWG), dim3(512),
                               (void**)args, 0, stream);
}